// Round 2
// baseline (498.053 us; speedup 1.0000x reference)
//
#include <hip/hip_runtime.h>
#include <hip/hip_bf16.h>

typedef __attribute__((ext_vector_type(8))) short bf16x8;
typedef __attribute__((ext_vector_type(4))) float f32x4;

namespace {

constexpr int kT = 16;
constexpr int kC = 256;
constexpr int kHeads = 8;
constexpr int kHW = 1024;
constexpr int kHWT = 4;   // hw positions per workgroup (one per wave)

// LDS layout (elements = ushort/bf16)
constexpr int kXsTStride = kC * kHWT + 8;        // 1032: X tile [t][c*4+hwt], padded
constexpr int kXSize = kT * kXsTStride;          // 16512
constexpr int kWsOff = kXSize;                   // weight slice: 32 rows x 264
constexpr int kWsStride = 264;
constexpr int kWsSize = 32 * kWsStride;          // 8448
constexpr int kQbOff = kWsOff + kWsSize;         // 24960
constexpr int kQbWave = 1792;                    // per wave: q 512 | k 512 | vT 512 | P 256
constexpr int kLdsElems = kQbOff + 4 * kQbWave;  // 32128 elems = 64256 B
static_assert(kLdsElems * 2 <= 65536, "LDS budget");

__device__ __forceinline__ unsigned short f2bf(float f) {
  unsigned int x;
  __builtin_memcpy(&x, &f, 4);
  x += 0x7fff + ((x >> 16) & 1);  // round-to-nearest-even
  return (unsigned short)(x >> 16);
}
__device__ __forceinline__ unsigned int pack2(float a, float b) {
  return (unsigned int)f2bf(a) | ((unsigned int)f2bf(b) << 16);
}

__global__ __launch_bounds__(256, 2) void fused_temporal_attn(
    const float* __restrict__ x,     // (4,16,256,32,32) fp32
    const float* __restrict__ rel,   // (8,16,16) fp32
    const float* __restrict__ wqkv,  // (768,256) fp32
    const float* __restrict__ bqkv,  // (768,) fp32
    const float* __restrict__ wout,  // (256,256) fp32
    const float* __restrict__ bout,  // (256,) fp32
    float* __restrict__ out) {       // (4,16,256,32,32) fp32
  __shared__ __align__(16) unsigned short smem[kLdsElems];
  const int tid = threadIdx.x;
  const int lane = tid & 63;
  const int wave = tid >> 6;   // 0..3 == hwt index, one hw per wave
  const int quad = lane >> 4;
  const int lrow = lane & 15;
  const int b = blockIdx.x >> 8;
  const int tile = blockIdx.x & 255;
  const int hw0 = tile * kHWT;

  // ---- Phase 0: stage X tile -> LDS bf16 [t][c][hwt] ----
  {
    const float* xb = x + (size_t)b * kT * kC * kHW + hw0;
#pragma unroll
    for (int it = 0; it < 16; ++it) {
      int idx = it * 256 + tid;  // t*256 + c
      int t = idx >> 8, c = idx & 255;
      const float4 v = *(const float4*)(xb + (size_t)(t * kC + c) * kHW);
      uint2 p;
      p.x = pack2(v.x, v.y);
      p.y = pack2(v.z, v.w);
      *(uint2*)&smem[t * kXsTStride + c * kHWT] = p;
    }
  }
  __syncthreads();

  // ---- cache MFMA A-fragments of X for this wave's hw (m=t, k=c) ----
  // A layout: lane holds A[m=lane&15][k=quad*8+j], j=0..7, k-chunk = ks*32
  bf16x8 ax[8];
#pragma unroll
  for (int ks = 0; ks < 8; ++ks) {
    bf16x8 f;
#pragma unroll
    for (int j = 0; j < 8; ++j) {
      int c = ks * 32 + quad * 8 + j;
      f[j] = (short)smem[lrow * kXsTStride + c * kHWT + wave];
    }
    ax[ks] = f;
  }

  unsigned short* qb = &smem[kQbOff + wave * kQbWave];
  unsigned short* kbuf = qb + 512;
  unsigned short* vtb = qb + 1024;  // v transposed: [d][j]
  unsigned short* pb = qb + 1536;

  const f32x4 zero4 = {0.f, 0.f, 0.f, 0.f};
  bf16x8 ao[8];  // out-proj A-fragments, one per head (e-chunk == head)

  for (int head = 0; head < kHeads; ++head) {
    for (int sel = 0; sel < 3; ++sel) {  // 0:q 1:k 2:v
      __syncthreads();
      {  // stage 32-row weight slice wqkv[sel*256 + head*32 + d][:] -> Ws (bf16)
        const float* wb = wqkv + (size_t)(sel * 256 + head * 32) * kC;
#pragma unroll
        for (int i = 0; i < 8; ++i) {
          int seg = i * 256 + tid;      // 2048 segments of 4 floats
          int d = seg >> 6, s = seg & 63;
          const float4 v = *(const float4*)(wb + d * kC + s * 4);
          uint2 p;
          p.x = pack2(v.x, v.y);
          p.y = pack2(v.z, v.w);
          *(uint2*)&smem[kWsOff + d * kWsStride + s * 4] = p;
        }
      }
      __syncthreads();
      // (16 x 32) = X_hw @ Wsel^T + bias ; B[k=c][n=d] = Wsel[d][c]
      float bias0 = bqkv[sel * 256 + head * 32 + lrow];
      float bias1 = bqkv[sel * 256 + head * 32 + 16 + lrow];
      f32x4 acc0 = {bias0, bias0, bias0, bias0};
      f32x4 acc1 = {bias1, bias1, bias1, bias1};
#pragma unroll
      for (int ks = 0; ks < 8; ++ks) {
        bf16x8 b0 = *(const bf16x8*)&smem[kWsOff + lrow * kWsStride + ks * 32 + quad * 8];
        bf16x8 b1 = *(const bf16x8*)&smem[kWsOff + (16 + lrow) * kWsStride + ks * 32 + quad * 8];
        acc0 = __builtin_amdgcn_mfma_f32_16x16x32_bf16(ax[ks], b0, acc0, 0, 0, 0);
        acc1 = __builtin_amdgcn_mfma_f32_16x16x32_bf16(ax[ks], b1, acc1, 0, 0, 0);
      }
      // C/D layout: lane holds row=quad*4+r, col=lane&15
      if (sel < 2) {
        unsigned short* dst = sel ? kbuf : qb;  // [t][d], stride 32
#pragma unroll
        for (int r = 0; r < 4; ++r) {
          int row = quad * 4 + r;
          dst[row * 32 + lrow] = f2bf(acc0[r]);
          dst[row * 32 + 16 + lrow] = f2bf(acc1[r]);
        }
      } else {  // v stored transposed: vT[d][j], stride 16
#pragma unroll
        for (int r = 0; r < 4; ++r) {
          int row = quad * 4 + r;  // key index j
          vtb[lrow * 16 + row] = f2bf(acc0[r]);
          vtb[(16 + lrow) * 16 + row] = f2bf(acc1[r]);
        }
      }
    }

    // ---- attention for this head (per wave / per hw) ----
    // sim[i][j] = sum_d q[i][d] k[j][d]; A=q (m=i,k=d), B[k=d][n=j]=k[j][d]
    bf16x8 qf = *(const bf16x8*)&qb[lrow * 32 + quad * 8];
    bf16x8 kf = *(const bf16x8*)&kbuf[lrow * 32 + quad * 8];
    f32x4 sim = __builtin_amdgcn_mfma_f32_16x16x32_bf16(qf, kf, zero4, 0, 0, 0);
    const float scale = 0.17677669529663687f;  // 32^-0.5
    float p[4], rsum[4];
#pragma unroll
    for (int r = 0; r < 4; ++r) {
      int i = quad * 4 + r;
      float v = sim[r] * scale + rel[head * 256 + i * 16 + lrow];
      float m = v;
      for (int off = 8; off; off >>= 1) m = fmaxf(m, __shfl_xor(m, off));
      float e = __expf(v - m);
      float s = e;
      for (int off = 8; off; off >>= 1) s += __shfl_xor(s, off);
      p[r] = e;       // unnormalized; normalize after P@V in fp32
      rsum[r] = s;
    }
#pragma unroll
    for (int r = 0; r < 4; ++r) pb[(quad * 4 + r) * 16 + lrow] = f2bf(p[r]);

    // out[i][d] = sum_j P[i][j] v[j][d]; pad k 16->32 with zeroed quads 2,3
    bf16x8 pf, vf0, vf1;
    if (quad < 2) {
      pf = *(const bf16x8*)&pb[lrow * 16 + quad * 8];
      vf0 = *(const bf16x8*)&vtb[lrow * 16 + quad * 8];
      vf1 = *(const bf16x8*)&vtb[(16 + lrow) * 16 + quad * 8];
    } else {
#pragma unroll
      for (int j = 0; j < 8; ++j) { pf[j] = 0; vf0[j] = 0; vf1[j] = 0; }
    }
    f32x4 o0 = __builtin_amdgcn_mfma_f32_16x16x32_bf16(pf, vf0, zero4, 0, 0, 0);
    f32x4 o1 = __builtin_amdgcn_mfma_f32_16x16x32_bf16(pf, vf1, zero4, 0, 0, 0);

    // bounce O-slice through qb (dead now) to convert C/D layout -> A layout.
    // head h's 32 columns are exactly out-proj k-chunk ks==h.
#pragma unroll
    for (int r = 0; r < 4; ++r) {
      int t = quad * 4 + r;
      float inv = 1.0f / rsum[r];
      qb[t * 32 + lrow] = f2bf(o0[r] * inv);
      qb[t * 32 + 16 + lrow] = f2bf(o1[r] * inv);
    }
    ao[head] = *(const bf16x8*)&qb[lrow * 32 + quad * 8];
  }  // head loop

  // ---- Phase 2: y = O @ wout^T + bout (16 x 256), own-wave data only ----
  float* ob = out + (size_t)b * kT * kC * kHW + hw0 + wave;
#pragma unroll 1
  for (int nt = 0; nt < 16; ++nt) {
    int c = nt * 16 + lrow;
    float bias = bout[c];
    f32x4 y = {bias, bias, bias, bias};
#pragma unroll
    for (int ks = 0; ks < 8; ++ks) {
      const float4 w0 = *(const float4*)(wout + (size_t)c * kC + ks * 32 + quad * 8);
      const float4 w1 = *(const float4*)(wout + (size_t)c * kC + ks * 32 + quad * 8 + 4);
      bf16x8 wf;
      wf[0] = (short)f2bf(w0.x); wf[1] = (short)f2bf(w0.y);
      wf[2] = (short)f2bf(w0.z); wf[3] = (short)f2bf(w0.w);
      wf[4] = (short)f2bf(w1.x); wf[5] = (short)f2bf(w1.y);
      wf[6] = (short)f2bf(w1.z); wf[7] = (short)f2bf(w1.w);
      y = __builtin_amdgcn_mfma_f32_16x16x32_bf16(ao[ks], wf, y, 0, 0, 0);
    }
#pragma unroll
    for (int r = 0; r < 4; ++r) {
      int t = quad * 4 + r;
      ob[(size_t)(t * kC + c) * kHW] = y[r];
    }
  }
}

}  // namespace

extern "C" void kernel_launch(void* const* d_in, const int* in_sizes, int n_in,
                              void* d_out, int out_size, void* d_ws, size_t ws_size,
                              hipStream_t stream) {
  const float* x = (const float*)d_in[0];
  const float* rel = (const float*)d_in[1];
  const float* wqkv = (const float*)d_in[2];
  const float* bqkv = (const float*)d_in[3];
  const float* wout = (const float*)d_in[4];
  const float* bout = (const float*)d_in[5];
  float* out = (float*)d_out;
  (void)in_sizes; (void)n_in; (void)out_size; (void)d_ws; (void)ws_size;
  dim3 grid(4 * (kHW / kHWT));  // 1024 blocks: b * 256 hw-tiles
  fused_temporal_attn<<<grid, dim3(256), 0, stream>>>(x, rel, wqkv, bqkv, wout, bout, out);
}

// Round 3
// 300.820 us; speedup vs baseline: 1.6557x; 1.6557x over previous
//
#include <hip/hip_runtime.h>
#include <hip/hip_bf16.h>

typedef __attribute__((ext_vector_type(8))) short bf16x8;
typedef __attribute__((ext_vector_type(4))) float f32x4;
typedef unsigned short ushort_t;

namespace {

constexpr int kT = 16;
constexpr int kC = 256;
constexpr int kHW = 1024;

__device__ __forceinline__ unsigned short f2bf(float f) {
  unsigned int x;
  __builtin_memcpy(&x, &f, 4);
  x += 0x7fff + ((x >> 16) & 1);  // round-to-nearest-even
  return (unsigned short)(x >> 16);
}
__device__ __forceinline__ unsigned int pack2(float a, float b) {
  return (unsigned int)f2bf(a) | ((unsigned int)f2bf(b) << 16);
}

// ============================ prep kernels ============================

// x (b,t,c,hw) fp32 -> xT (b,hw,t,c) bf16. Block = (b,t,c-chunk64,hw-chunk64).
__global__ __launch_bounds__(256) void prep_x(const float* __restrict__ x,
                                              unsigned short* __restrict__ xT) {
  __shared__ unsigned short ts[64 * 72];  // [hw][c], pad 64->72
  const int bx = blockIdx.x;
  const int cc = bx & 3, hc = (bx >> 2) & 15, t = (bx >> 6) & 15, b = bx >> 10;
  const int c0 = cc * 64, hw0 = hc * 64;
  const int tid = threadIdx.x;
  {
    const int ci = tid >> 2, j = tid & 3;
    const float* xrow = x + (((size_t)(b * 16 + t) * 256 + c0 + ci) * 1024) + hw0;
#pragma unroll
    for (int u = 0; u < 4; ++u) {
      const int chunk = j + u * 4;  // 0..15
      const float4 v = *(const float4*)(xrow + chunk * 4);
      const int hwl = chunk * 4;
      ts[(hwl + 0) * 72 + ci] = f2bf(v.x);
      ts[(hwl + 1) * 72 + ci] = f2bf(v.y);
      ts[(hwl + 2) * 72 + ci] = f2bf(v.z);
      ts[(hwl + 3) * 72 + ci] = f2bf(v.w);
    }
  }
  __syncthreads();
  {
    const int hwp = tid >> 2, jp = tid & 3;
    const uint4 a = *(const uint4*)&ts[hwp * 72 + jp * 16];
    const uint4 bq = *(const uint4*)&ts[hwp * 72 + jp * 16 + 8];
    unsigned short* dst =
        xT + ((size_t)((b * 1024 + hw0 + hwp) * 16 + t) * 256) + c0 + jp * 16;
    *(uint4*)dst = a;
    *(uint4*)(dst + 8) = bq;
  }
}

// fp32 -> bf16 weight conversion (wqkv 196608 floats, wout 65536 floats)
__global__ __launch_bounds__(256) void prep_w(const float* __restrict__ wqkv,
                                              const float* __restrict__ wout,
                                              unsigned short* __restrict__ wq_bf,
                                              unsigned short* __restrict__ wo_bf) {
  const int i = blockIdx.x * 256 + threadIdx.x;  // float4 index, 65536 total
  const float* src;
  unsigned short* dst;
  int off;
  if (i < 49152) { src = wqkv; dst = wq_bf; off = i; }
  else           { src = wout; dst = wo_bf; off = i - 49152; }
  const float4 v = *(const float4*)(src + (size_t)off * 4);
  uint2 p;
  p.x = pack2(v.x, v.y);
  p.y = pack2(v.z, v.w);
  *(uint2*)(dst + (size_t)off * 4) = p;
}

// ============================ main kernel ============================
// 512 thr = 8 waves; wave handles 2 hw sites; block = 16 consecutive hw.
// No __syncthreads; per-wave private LDS bounce only.
// Per-wave-per-site LDS (ushort elems): q 640 (stride 40) | k 640 (stride 40,
// P overlays first 256) | vT 512 (stride 16). Total 1792/site.
constexpr int kSiteLds = 1792;
constexpr int kMainLds = 8 * 2 * kSiteLds;  // 28672 elems = 57344 B

__global__ __launch_bounds__(512, 2) void attn_main(
    const unsigned short* __restrict__ xT,    // (4,1024,16,256) bf16
    const float* __restrict__ rel,            // (8,16,16) fp32
    const unsigned short* __restrict__ wqkv,  // (768,256) bf16
    const float* __restrict__ bqkv,           // (768,) fp32
    const unsigned short* __restrict__ wout,  // (256,256) bf16
    const float* __restrict__ bout,           // (256,) fp32
    float* __restrict__ out) {                // (4,16,256,32,32) fp32
  __shared__ __align__(16) unsigned short smem[kMainLds];
  const int tid = threadIdx.x;
  const int lane = tid & 63;
  const int wave = tid >> 6;  // 0..7
  const int quad = lane >> 4;
  const int lrow = lane & 15;
  const int b = blockIdx.x >> 6;
  const int hw0 = (blockIdx.x & 63) * 16;
  const int site0 = hw0 + wave * 2;

  unsigned short* wb = &smem[wave * 2 * kSiteLds];

  // ---- load A-fragments of X for both sites (direct, aligned 16B/lane) ----
  bf16x8 ax[2][8];
#pragma unroll
  for (int s = 0; s < 2; ++s) {
    const unsigned short* xs = xT + ((size_t)(b * 1024 + site0 + s) << 12);
#pragma unroll
    for (int ks = 0; ks < 8; ++ks)
      ax[s][ks] = *(const bf16x8*)(xs + lrow * 256 + ks * 32 + quad * 8);
  }

  const f32x4 zero4 = {0.f, 0.f, 0.f, 0.f};
  const float scale = 0.17677669529663687f;  // 32^-0.5
  bf16x8 ao[2][8];

  for (int h = 0; h < 8; ++h) {
    // ---- Q,K,V projection: B-frags streamed from global (L2-resident) ----
    const unsigned short* wq = wqkv + (size_t)(h * 32) * 256;
    const unsigned short* wk = wq + 256 * 256;
    const unsigned short* wv = wq + 512 * 256;
    f32x4 qa[2][2], ka[2][2], va[2][2];
#pragma unroll
    for (int m = 0; m < 2; ++m) {
      const float bq = bqkv[h * 32 + m * 16 + lrow];
      const float bk = bqkv[256 + h * 32 + m * 16 + lrow];
      const float bv = bqkv[512 + h * 32 + m * 16 + lrow];
#pragma unroll
      for (int s = 0; s < 2; ++s) {
        qa[s][m] = f32x4{bq, bq, bq, bq};
        ka[s][m] = f32x4{bk, bk, bk, bk};
        va[s][m] = f32x4{bv, bv, bv, bv};
      }
    }
#pragma unroll
    for (int ks = 0; ks < 8; ++ks) {
      const int fo = lrow * 256 + ks * 32 + quad * 8;
      const bf16x8 q0 = *(const bf16x8*)(wq + fo);
      const bf16x8 q1 = *(const bf16x8*)(wq + 16 * 256 + fo);
      const bf16x8 k0 = *(const bf16x8*)(wk + fo);
      const bf16x8 k1 = *(const bf16x8*)(wk + 16 * 256 + fo);
      const bf16x8 v0 = *(const bf16x8*)(wv + fo);
      const bf16x8 v1 = *(const bf16x8*)(wv + 16 * 256 + fo);
#pragma unroll
      for (int s = 0; s < 2; ++s) {
        qa[s][0] = __builtin_amdgcn_mfma_f32_16x16x32_bf16(ax[s][ks], q0, qa[s][0], 0, 0, 0);
        qa[s][1] = __builtin_amdgcn_mfma_f32_16x16x32_bf16(ax[s][ks], q1, qa[s][1], 0, 0, 0);
        ka[s][0] = __builtin_amdgcn_mfma_f32_16x16x32_bf16(ax[s][ks], k0, ka[s][0], 0, 0, 0);
        ka[s][1] = __builtin_amdgcn_mfma_f32_16x16x32_bf16(ax[s][ks], k1, ka[s][1], 0, 0, 0);
        va[s][0] = __builtin_amdgcn_mfma_f32_16x16x32_bf16(ax[s][ks], v0, va[s][0], 0, 0, 0);
        va[s][1] = __builtin_amdgcn_mfma_f32_16x16x32_bf16(ax[s][ks], v1, va[s][1], 0, 0, 0);
      }
    }
    // ---- bounce q,k,vT through private LDS (C/D layout -> A/B layouts) ----
#pragma unroll
    for (int s = 0; s < 2; ++s) {
      unsigned short* qb = wb + s * kSiteLds;
      unsigned short* kb = qb + 640;
      unsigned short* vt = qb + 1280;
#pragma unroll
      for (int r = 0; r < 4; ++r) {
        const int row = quad * 4 + r;
        qb[row * 40 + lrow] = f2bf(qa[s][0][r]);
        qb[row * 40 + 16 + lrow] = f2bf(qa[s][1][r]);
        kb[row * 40 + lrow] = f2bf(ka[s][0][r]);
        kb[row * 40 + 16 + lrow] = f2bf(ka[s][1][r]);
        vt[lrow * 16 + row] = f2bf(va[s][0][r]);           // vT[d][j]
        vt[(16 + lrow) * 16 + row] = f2bf(va[s][1][r]);
      }
    }
    // ---- sim + softmax (both sites before P overwrites kb) ----
    float p[2][4], inv[2][4];
#pragma unroll
    for (int s = 0; s < 2; ++s) {
      unsigned short* qb = wb + s * kSiteLds;
      unsigned short* kb = qb + 640;
      const bf16x8 qf = *(const bf16x8*)&qb[lrow * 40 + quad * 8];
      const bf16x8 kf = *(const bf16x8*)&kb[lrow * 40 + quad * 8];
      const f32x4 sim = __builtin_amdgcn_mfma_f32_16x16x32_bf16(qf, kf, zero4, 0, 0, 0);
#pragma unroll
      for (int r = 0; r < 4; ++r) {
        const int i = quad * 4 + r;
        const float v = sim[r] * scale + rel[h * 256 + i * 16 + lrow];
        float m = v;
        for (int off = 8; off; off >>= 1) m = fmaxf(m, __shfl_xor(m, off));
        const float e = __expf(v - m);
        float sum = e;
        for (int off = 8; off; off >>= 1) sum += __shfl_xor(sum, off);
        p[s][r] = e;
        inv[s][r] = 1.0f / sum;
      }
    }
    // ---- P@V, normalize, capture ao[h] (A-layout via qb bounce) ----
#pragma unroll
    for (int s = 0; s < 2; ++s) {
      unsigned short* qb = wb + s * kSiteLds;
      unsigned short* pb = qb + 640;  // overlays kb (dead)
      unsigned short* vt = qb + 1280;
#pragma unroll
      for (int r = 0; r < 4; ++r) pb[(quad * 4 + r) * 16 + lrow] = f2bf(p[s][r]);
      bf16x8 pf, vf0, vf1;
      if (quad < 2) {
        pf = *(const bf16x8*)&pb[lrow * 16 + quad * 8];
        vf0 = *(const bf16x8*)&vt[lrow * 16 + quad * 8];
        vf1 = *(const bf16x8*)&vt[(16 + lrow) * 16 + quad * 8];
      } else {
#pragma unroll
        for (int j = 0; j < 8; ++j) { pf[j] = 0; vf0[j] = 0; vf1[j] = 0; }
      }
      const f32x4 o0 = __builtin_amdgcn_mfma_f32_16x16x32_bf16(pf, vf0, zero4, 0, 0, 0);
      const f32x4 o1 = __builtin_amdgcn_mfma_f32_16x16x32_bf16(pf, vf1, zero4, 0, 0, 0);
#pragma unroll
      for (int r = 0; r < 4; ++r) {
        const int t = quad * 4 + r;
        qb[t * 32 + lrow] = f2bf(o0[r] * inv[s][r]);
        qb[t * 32 + 16 + lrow] = f2bf(o1[r] * inv[s][r]);
      }
      ao[s][h] = *(const bf16x8*)&qb[lrow * 32 + quad * 8];
    }
  }  // head loop

  // ---- epilogue: y = O @ wout^T + bout ----
  float* ob = out + ((size_t)b << 22) + site0;
#pragma unroll 1
  for (int nt = 0; nt < 16; ++nt) {
    const int c = nt * 16 + lrow;
    const float bias = bout[c];
    f32x4 y0 = {bias, bias, bias, bias};
    f32x4 y1 = {bias, bias, bias, bias};
#pragma unroll
    for (int ks = 0; ks < 8; ++ks) {
      const bf16x8 wf = *(const bf16x8*)(wout + (size_t)c * 256 + ks * 32 + quad * 8);
      y0 = __builtin_amdgcn_mfma_f32_16x16x32_bf16(ao[0][ks], wf, y0, 0, 0, 0);
      y1 = __builtin_amdgcn_mfma_f32_16x16x32_bf16(ao[1][ks], wf, y1, 0, 0, 0);
    }
#pragma unroll
    for (int r = 0; r < 4; ++r) {
      const int t = quad * 4 + r;
      ob[(size_t)(t * 256 + c) * 1024] = y0[r];
      ob[(size_t)(t * 256 + c) * 1024 + 1] = y1[r];
    }
  }
}

// ============================ fallback (round-2, passed) ============================
constexpr int kHWT = 4;
constexpr int kXsTStride = kC * kHWT + 8;
constexpr int kXSize = kT * kXsTStride;
constexpr int kWsOff = kXSize;
constexpr int kWsStride = 264;
constexpr int kWsSize = 32 * kWsStride;
constexpr int kQbOff = kWsOff + kWsSize;
constexpr int kQbWave = 1792;
constexpr int kLdsElems = kQbOff + 4 * kQbWave;

__global__ __launch_bounds__(256, 2) void fused_temporal_attn(
    const float* __restrict__ x, const float* __restrict__ rel,
    const float* __restrict__ wqkv, const float* __restrict__ bqkv,
    const float* __restrict__ wout, const float* __restrict__ bout,
    float* __restrict__ out) {
  __shared__ __align__(16) unsigned short smem[kLdsElems];
  const int tid = threadIdx.x;
  const int lane = tid & 63;
  const int wave = tid >> 6;
  const int quad = lane >> 4;
  const int lrow = lane & 15;
  const int b = blockIdx.x >> 8;
  const int tile = blockIdx.x & 255;
  const int hw0 = tile * kHWT;
  {
    const float* xb = x + (size_t)b * kT * kC * kHW + hw0;
#pragma unroll
    for (int it = 0; it < 16; ++it) {
      int idx = it * 256 + tid;
      int t = idx >> 8, c = idx & 255;
      const float4 v = *(const float4*)(xb + (size_t)(t * kC + c) * kHW);
      uint2 p;
      p.x = pack2(v.x, v.y);
      p.y = pack2(v.z, v.w);
      *(uint2*)&smem[t * kXsTStride + c * kHWT] = p;
    }
  }
  __syncthreads();
  bf16x8 ax[8];
#pragma unroll
  for (int ks = 0; ks < 8; ++ks) {
    bf16x8 f;
#pragma unroll
    for (int j = 0; j < 8; ++j) {
      int c = ks * 32 + quad * 8 + j;
      f[j] = (short)smem[lrow * kXsTStride + c * kHWT + wave];
    }
    ax[ks] = f;
  }
  unsigned short* qb = &smem[kQbOff + wave * kQbWave];
  unsigned short* kbuf = qb + 512;
  unsigned short* vtb = qb + 1024;
  unsigned short* pb = qb + 1536;
  const f32x4 zero4 = {0.f, 0.f, 0.f, 0.f};
  bf16x8 ao[8];
  for (int head = 0; head < 8; ++head) {
    for (int sel = 0; sel < 3; ++sel) {
      __syncthreads();
      {
        const float* wbp = wqkv + (size_t)(sel * 256 + head * 32) * kC;
#pragma unroll
        for (int i = 0; i < 8; ++i) {
          int seg = i * 256 + tid;
          int d = seg >> 6, s = seg & 63;
          const float4 v = *(const float4*)(wbp + d * kC + s * 4);
          uint2 p;
          p.x = pack2(v.x, v.y);
          p.y = pack2(v.z, v.w);
          *(uint2*)&smem[kWsOff + d * kWsStride + s * 4] = p;
        }
      }
      __syncthreads();
      float bias0 = bqkv[sel * 256 + head * 32 + lrow];
      float bias1 = bqkv[sel * 256 + head * 32 + 16 + lrow];
      f32x4 acc0 = {bias0, bias0, bias0, bias0};
      f32x4 acc1 = {bias1, bias1, bias1, bias1};
#pragma unroll
      for (int ks = 0; ks < 8; ++ks) {
        bf16x8 b0 = *(const bf16x8*)&smem[kWsOff + lrow * kWsStride + ks * 32 + quad * 8];
        bf16x8 b1 = *(const bf16x8*)&smem[kWsOff + (16 + lrow) * kWsStride + ks * 32 + quad * 8];
        acc0 = __builtin_amdgcn_mfma_f32_16x16x32_bf16(ax[ks], b0, acc0, 0, 0, 0);
        acc1 = __builtin_amdgcn_mfma_f32_16x16x32_bf16(ax[ks], b1, acc1, 0, 0, 0);
      }
      if (sel < 2) {
        unsigned short* dst = sel ? kbuf : qb;
#pragma unroll
        for (int r = 0; r < 4; ++r) {
          int row = quad * 4 + r;
          dst[row * 32 + lrow] = f2bf(acc0[r]);
          dst[row * 32 + 16 + lrow] = f2bf(acc1[r]);
        }
      } else {
#pragma unroll
        for (int r = 0; r < 4; ++r) {
          int row = quad * 4 + r;
          vtb[lrow * 16 + row] = f2bf(acc0[r]);
          vtb[(16 + lrow) * 16 + row] = f2bf(acc1[r]);
        }
      }
    }
    bf16x8 qf = *(const bf16x8*)&qb[lrow * 32 + quad * 8];
    bf16x8 kf = *(const bf16x8*)&kbuf[lrow * 32 + quad * 8];
    f32x4 sim = __builtin_amdgcn_mfma_f32_16x16x32_bf16(qf, kf, zero4, 0, 0, 0);
    const float scale = 0.17677669529663687f;
    float p[4], rsum[4];
#pragma unroll
    for (int r = 0; r < 4; ++r) {
      int i = quad * 4 + r;
      float v = sim[r] * scale + rel[head * 256 + i * 16 + lrow];
      float m = v;
      for (int off = 8; off; off >>= 1) m = fmaxf(m, __shfl_xor(m, off));
      float e = __expf(v - m);
      float s = e;
      for (int off = 8; off; off >>= 1) s += __shfl_xor(s, off);
      p[r] = e;
      rsum[r] = s;
    }
#pragma unroll
    for (int r = 0; r < 4; ++r) pb[(quad * 4 + r) * 16 + lrow] = f2bf(p[r]);
    bf16x8 pf, vf0, vf1;
    if (quad < 2) {
      pf = *(const bf16x8*)&pb[lrow * 16 + quad * 8];
      vf0 = *(const bf16x8*)&vtb[lrow * 16 + quad * 8];
      vf1 = *(const bf16x8*)&vtb[(16 + lrow) * 16 + quad * 8];
    } else {
#pragma unroll
      for (int j = 0; j < 8; ++j) { pf[j] = 0; vf0[j] = 0; vf1[j] = 0; }
    }
    f32x4 o0 = __builtin_amdgcn_mfma_f32_16x16x32_bf16(pf, vf0, zero4, 0, 0, 0);
    f32x4 o1 = __builtin_amdgcn_mfma_f32_16x16x32_bf16(pf, vf1, zero4, 0, 0, 0);
#pragma unroll
    for (int r = 0; r < 4; ++r) {
      int t = quad * 4 + r;
      float inv = 1.0f / rsum[r];
      qb[t * 32 + lrow] = f2bf(o0[r] * inv);
      qb[t * 32 + 16 + lrow] = f2bf(o1[r] * inv);
    }
    ao[head] = *(const bf16x8*)&qb[lrow * 32 + quad * 8];
  }
  float* ob = out + (size_t)b * kT * kC * kHW + hw0 + wave;
#pragma unroll 1
  for (int nt = 0; nt < 16; ++nt) {
    int c = nt * 16 + lrow;
    float bias = bout[c];
    f32x4 y = {bias, bias, bias, bias};
#pragma unroll
    for (int ks = 0; ks < 8; ++ks) {
      const float4 w0 = *(const float4*)(wout + (size_t)c * kC + ks * 32 + quad * 8);
      const float4 w1 = *(const float4*)(wout + (size_t)c * kC + ks * 32 + quad * 8 + 4);
      bf16x8 wf;
      wf[0] = (short)f2bf(w0.x); wf[1] = (short)f2bf(w0.y);
      wf[2] = (short)f2bf(w0.z); wf[3] = (short)f2bf(w0.w);
      wf[4] = (short)f2bf(w1.x); wf[5] = (short)f2bf(w1.y);
      wf[6] = (short)f2bf(w1.z); wf[7] = (short)f2bf(w1.w);
      y = __builtin_amdgcn_mfma_f32_16x16x32_bf16(ao[ks], wf, y, 0, 0, 0);
    }
#pragma unroll
    for (int r = 0; r < 4; ++r) {
      int t = quad * 4 + r;
      ob[(size_t)(t * kC + c) * kHW] = y[r];
    }
  }
}

}  // namespace

extern "C" void kernel_launch(void* const* d_in, const int* in_sizes, int n_in,
                              void* d_out, int out_size, void* d_ws, size_t ws_size,
                              hipStream_t stream) {
  const float* x = (const float*)d_in[0];
  const float* rel = (const float*)d_in[1];
  const float* wqkv = (const float*)d_in[2];
  const float* bqkv = (const float*)d_in[3];
  const float* wout = (const float*)d_in[4];
  const float* bout = (const float*)d_in[5];
  float* out = (float*)d_out;
  (void)in_sizes; (void)n_in; (void)out_size;

  constexpr size_t kXTElems = (size_t)4 * 1024 * 16 * 256;  // 16,777,216
  constexpr size_t kWqElems = 768 * 256;
  constexpr size_t kWoElems = 256 * 256;
  constexpr size_t kNeed = (kXTElems + kWqElems + kWoElems) * sizeof(unsigned short);

  if (ws_size >= kNeed) {
    unsigned short* xT = (unsigned short*)d_ws;
    unsigned short* wq_bf = xT + kXTElems;
    unsigned short* wo_bf = wq_bf + kWqElems;
    prep_x<<<4096, 256, 0, stream>>>(x, xT);
    prep_w<<<256, 256, 0, stream>>>(wqkv, wout, wq_bf, wo_bf);
    attn_main<<<256, 512, 0, stream>>>(xT, rel, wq_bf, bqkv, wo_bf, bout, out);
  } else {
    fused_temporal_attn<<<1024, 256, 0, stream>>>(x, rel, wqkv, bqkv, wout, bout, out);
  }
}

// Round 4
// 243.630 us; speedup vs baseline: 2.0443x; 1.2347x over previous
//
#include <hip/hip_runtime.h>
#include <hip/hip_bf16.h>

typedef __attribute__((ext_vector_type(8))) short bf16x8;
typedef __attribute__((ext_vector_type(4))) float f32x4;
typedef __attribute__((ext_vector_type(16))) float f32x16;

namespace {

constexpr int kT = 16;
constexpr int kC = 256;
constexpr int kHW = 1024;

__device__ __forceinline__ unsigned short f2bf(float f) {
  unsigned int x;
  __builtin_memcpy(&x, &f, 4);
  x += 0x7fff + ((x >> 16) & 1);  // round-to-nearest-even
  return (unsigned short)(x >> 16);
}
__device__ __forceinline__ unsigned int pack2(float a, float b) {
  return (unsigned int)f2bf(a) | ((unsigned int)f2bf(b) << 16);
}

// ============================ prep kernel ============================
// blocks < 4096: x (b,t,c,hw) fp32 -> xT (b,hw,t,c) bf16  (r3-proven body)
// blocks >= 4096: weight reorder+convert -> wAll bf16 [1024 rows x 256]:
//   rows g*32..g*32+31 for g<24: (head=g/3, sel=g%3) rows of wqkv;
//   g in 24..31: wout rows (g-24)*32...
__global__ __launch_bounds__(256) void prep(const float* __restrict__ x,
                                            const float* __restrict__ wqkv,
                                            const float* __restrict__ wout,
                                            unsigned short* __restrict__ xT,
                                            unsigned short* __restrict__ wAll) {
  __shared__ unsigned short ts[64 * 72];
  const int bx = blockIdx.x;
  const int tid = threadIdx.x;
  if (bx < 4096) {
    const int cc = bx & 3, hc = (bx >> 2) & 15, t = (bx >> 6) & 15, b = bx >> 10;
    const int c0 = cc * 64, hw0 = hc * 64;
    {
      const int ci = tid >> 2, j = tid & 3;
      const float* xrow = x + (((size_t)(b * 16 + t) * 256 + c0 + ci) * 1024) + hw0;
#pragma unroll
      for (int u = 0; u < 4; ++u) {
        const int chunk = j + u * 4;
        const float4 v = *(const float4*)(xrow + chunk * 4);
        const int hwl = chunk * 4;
        ts[(hwl + 0) * 72 + ci] = f2bf(v.x);
        ts[(hwl + 1) * 72 + ci] = f2bf(v.y);
        ts[(hwl + 2) * 72 + ci] = f2bf(v.z);
        ts[(hwl + 3) * 72 + ci] = f2bf(v.w);
      }
    }
    __syncthreads();
    {
      const int hwp = tid >> 2, jp = tid & 3;
      const uint4 a = *(const uint4*)&ts[hwp * 72 + jp * 16];
      const uint4 bq = *(const uint4*)&ts[hwp * 72 + jp * 16 + 8];
      unsigned short* dst =
          xT + ((size_t)((b * 1024 + hw0 + hwp) * 16 + t) * 256) + c0 + jp * 16;
      *(uint4*)dst = a;
      *(uint4*)(dst + 8) = bq;
    }
  } else {
    const int g = bx - 4096;            // 0..31
    const int row_l = tid >> 3;         // 0..31
    const int seg = tid & 7;            // 8 segs x 32 elems
    const float* src;
    int srow;
    if (g < 24) { src = wqkv; srow = (g % 3) * 256 + (g / 3) * 32 + row_l; }
    else        { src = wout; srow = (g - 24) * 32 + row_l; }
    const float* s = src + (size_t)srow * 256 + seg * 32;
    unsigned short* d = wAll + ((size_t)(g * 32 + row_l)) * 256 + seg * 32;
#pragma unroll
    for (int u = 0; u < 8; ++u) {
      const float4 v = *(const float4*)(s + u * 4);
      uint2 p;
      p.x = pack2(v.x, v.y);
      p.y = pack2(v.z, v.w);
      *(uint2*)(d + u * 4) = p;
    }
  }
}

// ============================ main kernel ============================
// 512 thr = 8 waves; wave handles 2 consecutive hw sites via m=32 MFMA;
// block = 16 consecutive hw; grid 256. wqkv staged (dbuf LDS); wout from L2.
constexpr int kWBStride = 264;                 // 256 + 8 pad (elems)
constexpr int kWBTile = 32 * kWBStride;        // 8448 elems
constexpr int kWB = 2 * kWBTile;               // 16896 elems
constexpr int kSite = 1824;                    // per-wave: q640(s40)|k640(s40,P s24)|vt512(s16)|pad
constexpr int kSmem = kWB + 8 * kSite;         // 31488 elems = 62976 B
static_assert(kSmem * 2 <= 65536, "LDS budget");

__global__ __launch_bounds__(512, 2) void attn_main(
    const unsigned short* __restrict__ xT,    // (4,1024,16,256) bf16
    const float* __restrict__ rel,            // (8,16,16) fp32
    const unsigned short* __restrict__ wAll,  // (1024,256) bf16 reordered
    const float* __restrict__ bqkv,           // (768,) fp32
    const float* __restrict__ bout,           // (256,) fp32
    float* __restrict__ out) {                // (4,16,256,32,32) fp32
  __shared__ __align__(16) unsigned short smem[kSmem];
  const int tid = threadIdx.x;
  const int lane = tid & 63;
  const int wave = tid >> 6;
  const int quad = lane >> 4;
  const int lrow = lane & 15;
  const int half = lane >> 5;
  const int n32 = lane & 31;
  const int b = blockIdx.x >> 6;
  const int hw0 = (blockIdx.x & 63) * 16;
  const int site0 = hw0 + wave * 2;

  // ---- A-frags of X, m=32 = 2 sites stacked (m=lane&31: s=m>>4, t=m&15) ----
  bf16x8 ax[16];
  {
    const unsigned short* xs =
        xT + (((size_t)(b * 1024 + site0 + (n32 >> 4))) << 12) + lrow * 256;
#pragma unroll
    for (int ks = 0; ks < 16; ++ks)
      ax[ks] = *(const bf16x8*)(xs + ks * 16 + half * 8);
  }

  unsigned short* qb = smem + kWB + wave * kSite;
  unsigned short* kb = qb + 640;
  unsigned short* vt = qb + 1280;  // stride 16, [d][j]

  const int stageDst = (tid >> 4) * kWBStride + (tid & 15) * 16;
  const int stageSrcOff = (tid >> 4) * 256 + (tid & 15) * 16;

  // prefetch stage tile 0
  uint4 pr0, pr1;
  {
    const unsigned short* sp = wAll + stageSrcOff;
    pr0 = *(const uint4*)sp;
    pr1 = *(const uint4*)(sp + 8);
  }

  const f32x4 zero4 = {0.f, 0.f, 0.f, 0.f};
  const float scale = 0.17677669529663687f;  // 32^-0.5
  bf16x8 ao[2][8];

  // staged QKV tile: stage g from regs, prefetch g+1, 16-kstep 32x32x16 MFMA
  auto qkv_tile = [&](int g, float bias) -> f32x16 {
    __syncthreads();  // WB[g&1] free (consumers of g-2 done)
    unsigned short* WBc = smem + (g & 1) * kWBTile;
    *(uint4*)(WBc + stageDst) = pr0;
    *(uint4*)(WBc + stageDst + 8) = pr1;
    {
      const unsigned short* sp = wAll + (size_t)(g + 1) * 32 * 256 + stageSrcOff;
      pr0 = *(const uint4*)sp;
      pr1 = *(const uint4*)(sp + 8);
    }
    __syncthreads();  // WB[g&1] ready
    f32x16 acc;
#pragma unroll
    for (int i = 0; i < 16; ++i) acc[i] = bias;
    const unsigned short* br = WBc + n32 * kWBStride + half * 8;
#pragma unroll
    for (int ks = 0; ks < 16; ++ks) {
      const bf16x8 bf = *(const bf16x8*)(br + ks * 16);
      acc = __builtin_amdgcn_mfma_f32_32x32x16_bf16(ax[ks], bf, acc, 0, 0, 0);
    }
    return acc;
  };

#pragma unroll 1
  for (int h = 0; h < 8; ++h) {
    const f32x16 qacc = qkv_tile(h * 3 + 0, bqkv[h * 32 + n32]);
    const f32x16 kacc = qkv_tile(h * 3 + 1, bqkv[256 + h * 32 + n32]);
    const f32x16 vacc = qkv_tile(h * 3 + 2, bqkv[512 + h * 32 + n32]);
    float rl[4];
#pragma unroll
    for (int r = 0; r < 4; ++r) rl[r] = rel[h * 256 + (quad * 4 + r) * 16 + lrow];

#pragma unroll
    for (int s = 0; s < 2; ++s) {
      // C/D 32x32: reg=8s+rr -> row=16s+t, t=(rr&3)+8*(rr>>2)+4*half, col=n32
#pragma unroll
      for (int rr = 0; rr < 8; ++rr) {
        const int t = (rr & 3) + 8 * (rr >> 2) + 4 * half;
        qb[t * 40 + n32] = f2bf(qacc[8 * s + rr]);
        kb[t * 40 + n32] = f2bf(kacc[8 * s + rr]);
      }
#pragma unroll
      for (int rp = 0; rp < 4; ++rp) {  // vT[d][j], paired t writes (b32)
        const int rr = rp * 2;
        const int t = (rr & 3) + 8 * (rr >> 2) + 4 * half;
        *(unsigned int*)&vt[n32 * 16 + t] =
            pack2(vacc[8 * s + rr], vacc[8 * s + rr + 1]);
      }
      // sim (16x16x32): A=q[m=t][k=d], B[k=d][n=j]=k[j][d]
      const bf16x8 qf = *(const bf16x8*)(qb + lrow * 40 + quad * 8);
      const bf16x8 kf = *(const bf16x8*)(kb + lrow * 40 + quad * 8);
      const f32x4 sim = __builtin_amdgcn_mfma_f32_16x16x32_bf16(qf, kf, zero4, 0, 0, 0);
      float p[4], inv[4];
#pragma unroll
      for (int r = 0; r < 4; ++r) {
        const float v = sim[r] * scale + rl[r];
        float m = v;
        for (int off = 8; off; off >>= 1) m = fmaxf(m, __shfl_xor(m, off));
        const float e = __expf(v - m);
        float sum = e;
        for (int off = 8; off; off >>= 1) sum += __shfl_xor(sum, off);
        p[r] = e;
        inv[r] = 1.0f / sum;
      }
      unsigned short* pb = kb;  // P overlays k (dead), stride 24
#pragma unroll
      for (int r = 0; r < 4; ++r) pb[(quad * 4 + r) * 24 + lrow] = f2bf(p[r]);
      bf16x8 pf, vf0, vf1;
      if (quad < 2) {
        pf = *(const bf16x8*)(pb + lrow * 24 + quad * 8);
        vf0 = *(const bf16x8*)(vt + lrow * 16 + quad * 8);
        vf1 = *(const bf16x8*)(vt + (16 + lrow) * 16 + quad * 8);
      } else {
#pragma unroll
        for (int j = 0; j < 8; ++j) { pf[j] = 0; vf0[j] = 0; vf1[j] = 0; }
      }
      const f32x4 o0 = __builtin_amdgcn_mfma_f32_16x16x32_bf16(pf, vf0, zero4, 0, 0, 0);
      const f32x4 o1 = __builtin_amdgcn_mfma_f32_16x16x32_bf16(pf, vf1, zero4, 0, 0, 0);
#pragma unroll
      for (int r = 0; r < 4; ++r) {  // O bounce into qb (dead) -> A-layout
        const int t = quad * 4 + r;
        qb[t * 40 + lrow] = f2bf(o0[r] * inv[r]);
        qb[t * 40 + 16 + lrow] = f2bf(o1[r] * inv[r]);
      }
      ao[s][h] = *(const bf16x8*)(qb + lrow * 40 + quad * 8);
    }
  }  // head loop

  // ---- epilogue: y = O @ wout^T + bout; coalesced stores via fp32 LDS bounce ----
  __syncthreads();  // sitebufs/WB dead; fbuf overlays smem
  float* fbuf = (float*)smem;  // [t*32+c_l]*17 + hw_l  (512 lines x 17)
  float* ob = out + ((size_t)b << 22);
#pragma unroll 1
  for (int cc = 0; cc < 8; ++cc) {
#pragma unroll
    for (int sub = 0; sub < 2; ++sub) {
      const int c = cc * 32 + sub * 16 + lrow;
      const float bias = bout[c];
      f32x4 y0 = {bias, bias, bias, bias};
      f32x4 y1 = {bias, bias, bias, bias};
#pragma unroll
      for (int ks = 0; ks < 8; ++ks) {
        const bf16x8 wf =
            *(const bf16x8*)(wAll + (size_t)(768 + c) * 256 + ks * 32 + quad * 8);
        y0 = __builtin_amdgcn_mfma_f32_16x16x32_bf16(ao[0][ks], wf, y0, 0, 0, 0);
        y1 = __builtin_amdgcn_mfma_f32_16x16x32_bf16(ao[1][ks], wf, y1, 0, 0, 0);
      }
#pragma unroll
      for (int r = 0; r < 4; ++r) {
        const int t = quad * 4 + r;
        const int L = (t * 32 + sub * 16 + lrow) * 17 + wave * 2;
        fbuf[L] = y0[r];
        fbuf[L + 1] = y1[r];
      }
    }
    __syncthreads();
    {
      const int t = tid >> 5, cl = tid & 31;
      float v[16];
#pragma unroll
      for (int i = 0; i < 16; ++i) v[i] = fbuf[tid * 17 + i];
      float* dst = ob + ((size_t)(t * 256 + cc * 32 + cl)) * 1024 + hw0;
#pragma unroll
      for (int u = 0; u < 4; ++u) {
        float4 q;
        q.x = v[u * 4]; q.y = v[u * 4 + 1]; q.z = v[u * 4 + 2]; q.w = v[u * 4 + 3];
        *(float4*)(dst + u * 4) = q;
      }
    }
    __syncthreads();
  }
}

// ============================ fallback (round-2, passed) ============================
constexpr int kHWT = 4;
constexpr int kXsTStride = kC * kHWT + 8;
constexpr int kXSize = kT * kXsTStride;
constexpr int kWsOff = kXSize;
constexpr int kWsStride = 264;
constexpr int kWsSize = 32 * kWsStride;
constexpr int kQbOff = kWsOff + kWsSize;
constexpr int kQbWave = 1792;
constexpr int kLdsElems = kQbOff + 4 * kQbWave;

__global__ __launch_bounds__(256, 2) void fused_temporal_attn(
    const float* __restrict__ x, const float* __restrict__ rel,
    const float* __restrict__ wqkv, const float* __restrict__ bqkv,
    const float* __restrict__ wout, const float* __restrict__ bout,
    float* __restrict__ out) {
  __shared__ __align__(16) unsigned short smem[kLdsElems];
  const int tid = threadIdx.x;
  const int lane = tid & 63;
  const int wave = tid >> 6;
  const int quad = lane >> 4;
  const int lrow = lane & 15;
  const int b = blockIdx.x >> 8;
  const int tile = blockIdx.x & 255;
  const int hw0 = tile * kHWT;
  {
    const float* xb = x + (size_t)b * kT * kC * kHW + hw0;
#pragma unroll
    for (int it = 0; it < 16; ++it) {
      int idx = it * 256 + tid;
      int t = idx >> 8, c = idx & 255;
      const float4 v = *(const float4*)(xb + (size_t)(t * kC + c) * kHW);
      uint2 p;
      p.x = pack2(v.x, v.y);
      p.y = pack2(v.z, v.w);
      *(uint2*)&smem[t * kXsTStride + c * kHWT] = p;
    }
  }
  __syncthreads();
  bf16x8 ax[8];
#pragma unroll
  for (int ks = 0; ks < 8; ++ks) {
    bf16x8 f;
#pragma unroll
    for (int j = 0; j < 8; ++j) {
      int c = ks * 32 + quad * 8 + j;
      f[j] = (short)smem[lrow * kXsTStride + c * kHWT + wave];
    }
    ax[ks] = f;
  }
  unsigned short* qb = &smem[kQbOff + wave * kQbWave];
  unsigned short* kbuf = qb + 512;
  unsigned short* vtb = qb + 1024;
  unsigned short* pb = qb + 1536;
  const f32x4 zero4 = {0.f, 0.f, 0.f, 0.f};
  bf16x8 ao[8];
  for (int head = 0; head < 8; ++head) {
    for (int sel = 0; sel < 3; ++sel) {
      __syncthreads();
      {
        const float* wbp = wqkv + (size_t)(sel * 256 + head * 32) * kC;
#pragma unroll
        for (int i = 0; i < 8; ++i) {
          int seg = i * 256 + tid;
          int d = seg >> 6, s = seg & 63;
          const float4 v = *(const float4*)(wbp + d * kC + s * 4);
          uint2 p;
          p.x = pack2(v.x, v.y);
          p.y = pack2(v.z, v.w);
          *(uint2*)&smem[kWsOff + d * kWsStride + s * 4] = p;
        }
      }
      __syncthreads();
      float bias0 = bqkv[sel * 256 + head * 32 + lrow];
      float bias1 = bqkv[sel * 256 + head * 32 + 16 + lrow];
      f32x4 acc0 = {bias0, bias0, bias0, bias0};
      f32x4 acc1 = {bias1, bias1, bias1, bias1};
#pragma unroll
      for (int ks = 0; ks < 8; ++ks) {
        bf16x8 b0 = *(const bf16x8*)&smem[kWsOff + lrow * kWsStride + ks * 32 + quad * 8];
        bf16x8 b1 = *(const bf16x8*)&smem[kWsOff + (16 + lrow) * kWsStride + ks * 32 + quad * 8];
        acc0 = __builtin_amdgcn_mfma_f32_16x16x32_bf16(ax[ks], b0, acc0, 0, 0, 0);
        acc1 = __builtin_amdgcn_mfma_f32_16x16x32_bf16(ax[ks], b1, acc1, 0, 0, 0);
      }
      if (sel < 2) {
        unsigned short* dst = sel ? kbuf : qb;
#pragma unroll
        for (int r = 0; r < 4; ++r) {
          int row = quad * 4 + r;
          dst[row * 32 + lrow] = f2bf(acc0[r]);
          dst[row * 32 + 16 + lrow] = f2bf(acc1[r]);
        }
      } else {
#pragma unroll
        for (int r = 0; r < 4; ++r) {
          int row = quad * 4 + r;
          vtb[lrow * 16 + row] = f2bf(acc0[r]);
          vtb[(16 + lrow) * 16 + row] = f2bf(acc1[r]);
        }
      }
    }
    bf16x8 qf = *(const bf16x8*)&qb[lrow * 32 + quad * 8];
    bf16x8 kf = *(const bf16x8*)&kbuf[lrow * 32 + quad * 8];
    f32x4 sim = __builtin_amdgcn_mfma_f32_16x16x32_bf16(qf, kf, zero4, 0, 0, 0);
    const float scale = 0.17677669529663687f;
    float p[4], rsum[4];
#pragma unroll
    for (int r = 0; r < 4; ++r) {
      int i = quad * 4 + r;
      float v = sim[r] * scale + rel[head * 256 + i * 16 + lrow];
      float m = v;
      for (int off = 8; off; off >>= 1) m = fmaxf(m, __shfl_xor(m, off));
      float e = __expf(v - m);
      float s = e;
      for (int off = 8; off; off >>= 1) s += __shfl_xor(s, off);
      p[r] = e;
      rsum[r] = s;
    }
#pragma unroll
    for (int r = 0; r < 4; ++r) pb[(quad * 4 + r) * 16 + lrow] = f2bf(p[r]);
    bf16x8 pf, vf0, vf1;
    if (quad < 2) {
      pf = *(const bf16x8*)&pb[lrow * 16 + quad * 8];
      vf0 = *(const bf16x8*)&vtb[lrow * 16 + quad * 8];
      vf1 = *(const bf16x8*)&vtb[(16 + lrow) * 16 + quad * 8];
    } else {
#pragma unroll
      for (int j = 0; j < 8; ++j) { pf[j] = 0; vf0[j] = 0; vf1[j] = 0; }
    }
    f32x4 o0 = __builtin_amdgcn_mfma_f32_16x16x32_bf16(pf, vf0, zero4, 0, 0, 0);
    f32x4 o1 = __builtin_amdgcn_mfma_f32_16x16x32_bf16(pf, vf1, zero4, 0, 0, 0);
#pragma unroll
    for (int r = 0; r < 4; ++r) {
      int t = quad * 4 + r;
      float inv = 1.0f / rsum[r];
      qb[t * 32 + lrow] = f2bf(o0[r] * inv);
      qb[t * 32 + 16 + lrow] = f2bf(o1[r] * inv);
    }
    ao[head] = *(const bf16x8*)&qb[lrow * 32 + quad * 8];
  }
  float* ob = out + (size_t)b * kT * kC * kHW + hw0 + wave;
#pragma unroll 1
  for (int nt = 0; nt < 16; ++nt) {
    int c = nt * 16 + lrow;
    float bias = bout[c];
    f32x4 y = {bias, bias, bias, bias};
#pragma unroll
    for (int ks = 0; ks < 8; ++ks) {
      const float4 w0 = *(const float4*)(wout + (size_t)c * kC + ks * 32 + quad * 8);
      const float4 w1 = *(const float4*)(wout + (size_t)c * kC + ks * 32 + quad * 8 + 4);
      bf16x8 wf;
      wf[0] = (short)f2bf(w0.x); wf[1] = (short)f2bf(w0.y);
      wf[2] = (short)f2bf(w0.z); wf[3] = (short)f2bf(w0.w);
      wf[4] = (short)f2bf(w1.x); wf[5] = (short)f2bf(w1.y);
      wf[6] = (short)f2bf(w1.z); wf[7] = (short)f2bf(w1.w);
      y = __builtin_amdgcn_mfma_f32_16x16x32_bf16(ao[ks], wf, y, 0, 0, 0);
    }
#pragma unroll
    for (int r = 0; r < 4; ++r) {
      int t = quad * 4 + r;
      ob[(size_t)(t * kC + c) * kHW] = y[r];
    }
  }
}

}  // namespace

extern "C" void kernel_launch(void* const* d_in, const int* in_sizes, int n_in,
                              void* d_out, int out_size, void* d_ws, size_t ws_size,
                              hipStream_t stream) {
  const float* x = (const float*)d_in[0];
  const float* rel = (const float*)d_in[1];
  const float* wqkv = (const float*)d_in[2];
  const float* bqkv = (const float*)d_in[3];
  const float* wout = (const float*)d_in[4];
  const float* bout = (const float*)d_in[5];
  float* out = (float*)d_out;
  (void)in_sizes; (void)n_in; (void)out_size;

  constexpr size_t kXTElems = (size_t)4 * 1024 * 16 * 256;  // 16,777,216
  constexpr size_t kWAllElems = 1024 * 256;                 // 262,144
  constexpr size_t kNeed = (kXTElems + kWAllElems) * sizeof(unsigned short);

  if (ws_size >= kNeed) {
    unsigned short* xT = (unsigned short*)d_ws;
    unsigned short* wAll = xT + kXTElems;
    prep<<<4096 + 32, 256, 0, stream>>>(x, wqkv, wout, xT, wAll);
    attn_main<<<256, 512, 0, stream>>>(xT, rel, wAll, bqkv, bout, out);
  } else {
    fused_temporal_attn<<<1024, 256, 0, stream>>>(x, rel, wqkv, bqkv, wout, bout, out);
  }
}